// Round 1
// 311.531 us; speedup vs baseline: 1.0727x; 1.0727x over previous
//
#include <hip/hip_runtime.h>

#define DIM 64
#define LSTRIDE 68              // bf16 elems per row: 64 + 4 pad -> 34 dwords (2-way bank alias = free)
#define PLANE (DIM * LSTRIDE)   // 4352 ushorts = 8704 B per plane

typedef __attribute__((ext_vector_type(8))) short short8;
typedef __attribute__((ext_vector_type(16))) float f32x16;

#define MFMA(a, b, c) __builtin_amdgcn_mfma_f32_32x32x16_bf16((a), (b), (c), 0, 0, 0)

// packed f32 -> 2x bf16 (RNE), D[15:0]=bf16(a), D[31:16]=bf16(b)
__device__ __forceinline__ unsigned int cvt_pk_bf16(float a, float b) {
    unsigned int r;
    asm("v_cvt_pk_bf16_f32 %0, %1, %2" : "=v"(r) : "v"(a), "v"(b));
    return r;
}

// pack 4 f32 -> hi uint2 (4 bf16) + lo uint2 (4 bf16 residuals)
// residual = v - float(hi_bf16), exact in fp32; then RNE to bf16.
__device__ __forceinline__ void pack4(const float* v, uint2& hw, uint2& lw) {
    const unsigned int ph0 = cvt_pk_bf16(v[0], v[1]);
    const unsigned int ph1 = cvt_pk_bf16(v[2], v[3]);
    const float h0 = __uint_as_float(ph0 << 16);
    const float h1 = __uint_as_float(ph0 & 0xffff0000u);
    const float h2 = __uint_as_float(ph1 << 16);
    const float h3 = __uint_as_float(ph1 & 0xffff0000u);
    hw = make_uint2(ph0, ph1);
    lw = make_uint2(cvt_pk_bf16(v[0] - h0, v[1] - h1),
                    cvt_pk_bf16(v[2] - h2, v[3] - h3));
}

union FragU { short8 v; uint2 u2[2]; };

__device__ __forceinline__ short8 load_frag(const unsigned short* p) {
    FragU f;
    f.u2[0] = *(const uint2*)p;
    f.u2[1] = *(const uint2*)(p + 4);
    return f.v;
}

// planes: 0 Wh, 1 Wl (A / ZY / P), 2 Yh, 3 Yl, 4 Zh, 5 Zl
extern "C" __global__ void __launch_bounds__(256, 3)
isqrtm_kernel(const float* __restrict__ x, const int* __restrict__ iterN_p,
              float* __restrict__ out)
{
    __shared__ __align__(16) unsigned short pl[6][PLANE];

    const int t = threadIdx.x;
    const int b = blockIdx.x;
    const float* xg = x + (size_t)b * 4096;
    float* og = out + (size_t)b * 4096;
    const int iterN = iterN_p[0];

    const int lane = t & 63;

    // ---- trace (normA): every wave reduces the diagonal independently ----
    float tv = xg[lane * 65];
    #pragma unroll
    for (int o = 32; o > 0; o >>= 1) tv += __shfl_down(tv, o);
    const float tr  = __shfl(tv, 0);
    const float inv = 1.0f / tr;
    const float sc  = sqrtf(tr);

    // ---- build A (W planes) and Z = ZY0 = 1.5I - 0.5A ----
    #pragma unroll
    for (int ch = 0; ch < 4; ++ch) {
        const int e  = ch * 1024 + t * 4;
        const int i  = e >> 6, j0 = e & 63;
        const float4 xv = *(const float4*)(xg + e);
        const float av[4] = { xv.x * inv, xv.y * inv, xv.z * inv, xv.w * inv };
        float zv[4];
        #pragma unroll
        for (int q = 0; q < 4; ++q)
            zv[q] = fmaf(-0.5f, av[q], (i == j0 + q) ? 1.5f : 0.0f);
        uint2 ahw, alw, zhw, zlw;
        pack4(av, ahw, alw);
        pack4(zv, zhw, zlw);
        const int ad = i * LSTRIDE + j0;
        *(uint2*)&pl[0][ad] = ahw;
        *(uint2*)&pl[1][ad] = alw;
        *(uint2*)&pl[4][ad] = zhw;
        *(uint2*)&pl[5][ad] = zlw;
    }
    __syncthreads();

    // ---- wave / tile constants ----
    const int wv = t >> 6;
    const int wr = wv >> 1, wc = wv & 1;        // 32x32 tile coords
    const int m  = lane & 31, hh = lane >> 5;
    const int ra = (32 * wr + m) * LSTRIDE + 8 * hh;
    const int rb = (32 * wc + m) * LSTRIDE + 8 * hh;
    const int dql = 32 * wc + m - 32 * wr - 4 * hh;   // diag test: q + 8g == dql

    short8 yh[4], yl[4];                        // cached B-op fragments (Y)

    auto load_B = [&](int p_) {
        #pragma unroll
        for (int s = 0; s < 4; ++s) {
            yh[s] = load_frag(&pl[p_][rb + 16 * s]);
            yl[s] = load_frag(&pl[p_ + 1][rb + 16 * s]);
        }
    };

    // C = M(a_) @ Ycached, hi/lo 3-term
    auto matmul_cB = [&](int a_) -> f32x16 {
        f32x16 acc = {};
        #pragma unroll
        for (int s = 0; s < 4; ++s) {
            const short8 ah = load_frag(&pl[a_][ra + 16 * s]);
            const short8 al = load_frag(&pl[a_ + 1][ra + 16 * s]);
            acc = MFMA(ah, yh[s], acc);
            acc = MFMA(ah, yl[s], acc);
            acc = MFMA(al, yh[s], acc);
        }
        return acc;
    };

    // o1 = W @ Ycached, o2 = W @ M(b2_)  (shared W A-fragments)
    auto matmul2_cB = [&](int b2_, f32x16& o1, f32x16& o2) {
        o1 = {}; o2 = {};
        #pragma unroll
        for (int s = 0; s < 4; ++s) {
            const short8 ah  = load_frag(&pl[0][ra + 16 * s]);
            const short8 al  = load_frag(&pl[1][ra + 16 * s]);
            const short8 b2h = load_frag(&pl[b2_][rb + 16 * s]);
            const short8 b2l = load_frag(&pl[b2_ + 1][rb + 16 * s]);
            o1 = MFMA(ah, yh[s], o1); o1 = MFMA(ah, yl[s], o1); o1 = MFMA(al, yh[s], o1);
            o2 = MFMA(ah, b2h, o2);   o2 = MFMA(ah, b2l, o2);   o2 = MFMA(al, b2h, o2);
        }
    };

    // write C-layout tile into a plane pair, transposed (valid: result symmetric).
    auto write_tile = [&](int p_, const f32x16& acc, bool zyform) {
        #pragma unroll
        for (int g = 0; g < 4; ++g) {
            float v[4];
            #pragma unroll
            for (int q = 0; q < 4; ++q) {
                v[q] = acc[4 * g + q];
                if (zyform)
                    v[q] = fmaf(-0.5f, v[q], (q + 8 * g == dql) ? 1.5f : 0.0f);
            }
            uint2 hw, lw;
            pack4(v, hw, lw);
            const int ad = (32 * wc + m) * LSTRIDE + (32 * wr + 8 * g + 4 * hh);
            *(uint2*)&pl[p_][ad]     = hw;
            *(uint2*)&pl[p_ + 1][ad] = lw;
        }
    };

    auto write_global = [&](const f32x16& acc, float scale) {
        #pragma unroll
        for (int g = 0; g < 4; ++g)
            #pragma unroll
            for (int q = 0; q < 4; ++q) {
                const int rl = q + 8 * g + 4 * hh;
                og[(32 * wr + rl) * 64 + 32 * wc + m] = acc[4 * g + q] * scale;
            }
    };

    // ---- step 1: Y1 = A @ ZY0  (W as A-op, Z cached as B-op) ----
    {
        load_B(4);
        const f32x16 accY = matmul_cB(0);
        if (iterN < 2) { write_global(accY, sc); return; }
        write_tile(2, accY, false);              // Y planes
    }
    __syncthreads();

    // ---- loop: 3 matmuls / iteration, Y B-frags cached across both ----
    for (int it = 1; it < iterN - 1; ++it) {
        load_B(2);                               // Y as B-op (valid: post-sync)
        const f32x16 T = matmul_cB(4);           // Z @ Y
        write_tile(0, T, true);                  // W = 0.5*(3I - T)
        __syncthreads();
        f32x16 nY, nZ;
        matmul2_cB(4, nY, nZ);                   // nY = W@Y (=Y@ZY), nZ = W@Z
        __syncthreads();                         // all reads of Y,Z done
        write_tile(2, nY, false);
        write_tile(4, nZ, false);
        __syncthreads();
    }

    // ---- final: YZY = 0.5 * Y @ (3I - Z@Y), y = YZY * sqrt(normA) ----
    {
        load_B(2);                               // Y cached for both matmuls
        const f32x16 T = matmul_cB(4);           // Z @ Y
        write_tile(0, T, true);                  // W = P = 0.5*(3I - Z@Y)
        __syncthreads();
        const f32x16 O = matmul_cB(0);           // P @ Y (= Y @ P)
        write_global(O, sc);
    }
}

extern "C" void kernel_launch(void* const* d_in, const int* in_sizes, int n_in,
                              void* d_out, int out_size, void* d_ws, size_t ws_size,
                              hipStream_t stream) {
    const float* x = (const float*)d_in[0];
    const int* iterN = (const int*)d_in[1];
    float* out = (float*)d_out;
    const int B = in_sizes[0] / (DIM * DIM);   // 8192
    isqrtm_kernel<<<dim3(B), dim3(256), 0, stream>>>(x, iterN, out);
}

// Round 3
// 303.535 us; speedup vs baseline: 1.1009x; 1.0263x over previous
//
#include <hip/hip_runtime.h>

#define DIM 64
#define LSTRIDE 68              // bf16 elems per row: 64 + 4 pad -> 34 dwords (2-way bank alias = free)
#define PLANE (DIM * LSTRIDE)   // 4352 ushorts = 8704 B per plane

typedef __attribute__((ext_vector_type(8))) short short8;
typedef __attribute__((ext_vector_type(16))) float f32x16;

#define MFMA(a, b, c) __builtin_amdgcn_mfma_f32_32x32x16_bf16((a), (b), (c), 0, 0, 0)

// packed f32 -> 2x bf16 (RNE), D[15:0]=bf16(a), D[31:16]=bf16(b)
__device__ __forceinline__ unsigned int cvt_pk_bf16(float a, float b) {
    unsigned int r;
    asm("v_cvt_pk_bf16_f32 %0, %1, %2" : "=v"(r) : "v"(a), "v"(b));
    return r;
}

// pack 4 f32 -> hi uint2 (4 bf16) + lo uint2 (4 bf16 residuals)
__device__ __forceinline__ void pack4(const float* v, uint2& hw, uint2& lw) {
    const unsigned int ph0 = cvt_pk_bf16(v[0], v[1]);
    const unsigned int ph1 = cvt_pk_bf16(v[2], v[3]);
    const float h0 = __uint_as_float(ph0 << 16);
    const float h1 = __uint_as_float(ph0 & 0xffff0000u);
    const float h2 = __uint_as_float(ph1 << 16);
    const float h3 = __uint_as_float(ph1 & 0xffff0000u);
    hw = make_uint2(ph0, ph1);
    lw = make_uint2(cvt_pk_bf16(v[0] - h0, v[1] - h1),
                    cvt_pk_bf16(v[2] - h2, v[3] - h3));
}

union FragU { short8 v; uint2 u2[2]; };

__device__ __forceinline__ short8 load_frag(const unsigned short* p) {
    FragU f;
    f.u2[0] = *(const uint2*)p;
    f.u2[1] = *(const uint2*)(p + 4);
    return f.v;
}

// planes: 0 Wh, 1 Wl (A / ZY / P), 2 Yh, 3 Yl, 4 Zh, 5 Zl
// 3 waves / block: every intermediate matrix is symmetric (polynomials in SPD A
// commute), so tile C10 = C01^T. Waves compute only {C00, C01, C11}; the
// off-diag wave (wv==1) materializes both regions in LDS/global.
extern "C" __global__ void __launch_bounds__(192, 2)
isqrtm_kernel(const float* __restrict__ x, const int* __restrict__ iterN_p,
              float* __restrict__ out)
{
    __shared__ __align__(16) unsigned short pl[6][PLANE];

    const int t = threadIdx.x;
    const int b = blockIdx.x;
    const float* xg = x + (size_t)b * 4096;
    float* og = out + (size_t)b * 4096;
    const int iterN = iterN_p[0];

    const int lane = t & 63;

    // ---- trace (normA): every wave reduces the diagonal independently ----
    float tv = xg[lane * 65];
    #pragma unroll
    for (int o = 32; o > 0; o >>= 1) tv += __shfl_down(tv, o);
    const float tr  = __shfl(tv, 0);
    const float inv = 1.0f / tr;
    const float sc  = sqrtf(tr);

    // ---- build A (W planes) and Z = ZY0 = 1.5I - 0.5A ----
    auto build = [&](int e) {
        const int i  = e >> 6, j0 = e & 63;
        const float4 xv = *(const float4*)(xg + e);
        const float av[4] = { xv.x * inv, xv.y * inv, xv.z * inv, xv.w * inv };
        float zv[4];
        #pragma unroll
        for (int q = 0; q < 4; ++q)
            zv[q] = fmaf(-0.5f, av[q], (i == j0 + q) ? 1.5f : 0.0f);
        uint2 ahw, alw, zhw, zlw;
        pack4(av, ahw, alw);
        pack4(zv, zhw, zlw);
        const int ad = i * LSTRIDE + j0;
        *(uint2*)&pl[0][ad] = ahw;
        *(uint2*)&pl[1][ad] = alw;
        *(uint2*)&pl[4][ad] = zhw;
        *(uint2*)&pl[5][ad] = zlw;
    };
    #pragma unroll
    for (int ch = 0; ch < 5; ++ch) build(ch * 768 + t * 4);
    if (t < 64) build(3840 + t * 4);
    __syncthreads();

    // ---- wave / tile constants: wv 0,1,2 -> (wr,wc) = (0,0),(0,1),(1,1) ----
    const int wv = t >> 6;
    const int wr = wv >> 1;
    const int wc = (wv + 1) >> 1;
    const int m  = lane & 31, hh = lane >> 5;
    const int ra = (32 * wr + m) * LSTRIDE + 8 * hh;
    const int rb = (32 * wc + m) * LSTRIDE + 8 * hh;
    const int dql = 32 * wc + m - 32 * wr - 4 * hh;   // diag test: q + 8g == dql (never fires for wv==1)

    short8 yh[4], yl[4];                        // cached B-op fragments (Y)

    auto load_B = [&](int p_) {
        #pragma unroll
        for (int s = 0; s < 4; ++s) {
            yh[s] = load_frag(&pl[p_][rb + 16 * s]);
            yl[s] = load_frag(&pl[p_ + 1][rb + 16 * s]);
        }
    };

    // C = M(a_) @ Ycached, hi/lo 3-term
    auto matmul_cB = [&](int a_) -> f32x16 {
        f32x16 acc = {};
        #pragma unroll
        for (int s = 0; s < 4; ++s) {
            const short8 ah = load_frag(&pl[a_][ra + 16 * s]);
            const short8 al = load_frag(&pl[a_ + 1][ra + 16 * s]);
            acc = MFMA(ah, yh[s], acc);
            acc = MFMA(ah, yl[s], acc);
            acc = MFMA(al, yh[s], acc);
        }
        return acc;
    };

    // o1 = W @ Ycached, o2 = W @ M(b2_)  (shared W A-fragments)
    auto matmul2_cB = [&](int b2_, f32x16& o1, f32x16& o2) {
        o1 = {}; o2 = {};
        #pragma unroll
        for (int s = 0; s < 4; ++s) {
            const short8 ah  = load_frag(&pl[0][ra + 16 * s]);
            const short8 al  = load_frag(&pl[1][ra + 16 * s]);
            const short8 b2h = load_frag(&pl[b2_][rb + 16 * s]);
            const short8 b2l = load_frag(&pl[b2_ + 1][rb + 16 * s]);
            o1 = MFMA(ah, yh[s], o1); o1 = MFMA(ah, yl[s], o1); o1 = MFMA(al, yh[s], o1);
            o2 = MFMA(ah, b2h, o2);   o2 = MFMA(ah, b2l, o2);   o2 = MFMA(al, b2h, o2);
        }
    };

    // write C-layout tile into a plane pair, transposed (valid: result symmetric).
    // wv==1 additionally scatter-writes the untransposed C01 region (column
    // write: ds_write_b16 x16/plane, offsets fold to immediates off one base).
    auto write_tile = [&](int p_, const f32x16& acc, bool zyform) {
        #pragma unroll
        for (int g = 0; g < 4; ++g) {
            float v[4];
            #pragma unroll
            for (int q = 0; q < 4; ++q) {
                v[q] = acc[4 * g + q];
                if (zyform)
                    v[q] = fmaf(-0.5f, v[q], (q + 8 * g == dql) ? 1.5f : 0.0f);
            }
            uint2 hw, lw;
            pack4(v, hw, lw);
            const int ad = (32 * wc + m) * LSTRIDE + (32 * wr + 8 * g + 4 * hh);
            *(uint2*)&pl[p_][ad]     = hw;
            *(uint2*)&pl[p_ + 1][ad] = lw;
            if (wv == 1) {
                const int ad2 = (8 * g + 4 * hh) * LSTRIDE + 32 + m;  // wr==0
                unsigned short* ph = &pl[p_][ad2];
                unsigned short* po = &pl[p_ + 1][ad2];
                ph[0]           = (unsigned short)hw.x;
                ph[LSTRIDE]     = (unsigned short)(hw.x >> 16);
                ph[2 * LSTRIDE] = (unsigned short)hw.y;
                ph[3 * LSTRIDE] = (unsigned short)(hw.y >> 16);
                po[0]           = (unsigned short)lw.x;
                po[LSTRIDE]     = (unsigned short)(lw.x >> 16);
                po[2 * LSTRIDE] = (unsigned short)lw.y;
                po[3 * LSTRIDE] = (unsigned short)(lw.y >> 16);
            }
        }
    };

    auto write_global = [&](const f32x16& acc, float scale) {
        #pragma unroll
        for (int g = 0; g < 4; ++g) {
            #pragma unroll
            for (int q = 0; q < 4; ++q) {
                const int rl = q + 8 * g + 4 * hh;
                og[(32 * wr + rl) * 64 + 32 * wc + m] = acc[4 * g + q] * scale;
            }
            if (wv == 1) {
                // C10 region: row fixed per lane, cols contiguous -> float4
                const float4 o4 = make_float4(acc[4 * g]     * scale,
                                              acc[4 * g + 1] * scale,
                                              acc[4 * g + 2] * scale,
                                              acc[4 * g + 3] * scale);
                *(float4*)&og[(32 + m) * 64 + 8 * g + 4 * hh] = o4;
            }
        }
    };

    // ---- step 1: Y1 = A @ ZY0  (W as A-op, Z cached as B-op) ----
    {
        load_B(4);
        const f32x16 accY = matmul_cB(0);
        if (iterN < 2) { write_global(accY, sc); return; }
        write_tile(2, accY, false);              // Y planes
    }
    __syncthreads();

    // ---- loop: 3 matmuls / iteration, Y B-frags cached across both ----
    for (int it = 1; it < iterN - 1; ++it) {
        load_B(2);                               // Y as B-op (valid: post-sync)
        const f32x16 T = matmul_cB(4);           // Z @ Y
        write_tile(0, T, true);                  // W = 0.5*(3I - T)
        __syncthreads();
        f32x16 nY, nZ;
        matmul2_cB(4, nY, nZ);                   // nY = W@Y (=Y@ZY), nZ = W@Z
        __syncthreads();                         // all reads of Y,Z done
        write_tile(2, nY, false);
        write_tile(4, nZ, false);
        __syncthreads();
    }

    // ---- final: YZY = 0.5 * Y @ (3I - Z@Y), y = YZY * sqrt(normA) ----
    {
        load_B(2);                               // Y cached for both matmuls
        const f32x16 T = matmul_cB(4);           // Z @ Y
        write_tile(0, T, true);                  // W = P = 0.5*(3I - Z@Y)
        __syncthreads();
        const f32x16 O = matmul_cB(0);           // P @ Y (= Y @ P)
        write_global(O, sc);
    }
}

extern "C" void kernel_launch(void* const* d_in, const int* in_sizes, int n_in,
                              void* d_out, int out_size, void* d_ws, size_t ws_size,
                              hipStream_t stream) {
    const float* x = (const float*)d_in[0];
    const int* iterN = (const int*)d_in[1];
    float* out = (float*)d_out;
    const int B = in_sizes[0] / (DIM * DIM);   // 8192
    isqrtm_kernel<<<dim3(B), dim3(192), 0, stream>>>(x, iterN, out);
}